// Round 12
// baseline (41.293 us; speedup 1.0000x reference)
//
#include <hip/hip_runtime.h>
#include <math.h>

// Problem constants: N=32, CI=32, CO=32, H=64, W=64, K=2
#define NN 32
#define CI 32
#define CO 32
#define HH 64
#define WW 64
#define PLANE (HH * WW)
#define REPS 8   // PROBE: in-kernel repeat (see header). Revert to 1 after.

typedef __attribute__((ext_vector_type(8))) short bf16x8;   // MFMA A/B frag
typedef __attribute__((ext_vector_type(4))) float f32x4;    // MFMA C/D frag
typedef float v2f __attribute__((ext_vector_type(2)));

// float -> bf16 (round-to-nearest-even)
__device__ inline short f2bf(float f) {
    union { float f; unsigned u; } v; v.f = f;
    unsigned r = v.u + 0x7FFFu + ((v.u >> 16) & 1u);
    return (short)(r >> 16);
}

// ---------------------------------------------------------------------------
// PROBE ROUND (R12): body identical to R11 (13.42us single-shot; body ~8.3us
// by R10's marginal-dispatch arithmetic), wrapped in an 8x in-kernel repeat.
// Reps reuse resident waves -> no dispatch gap/ramp -> marginal per rep =
// steady-state throughput cost only. asm memory-clobber per rep prevents
// CSE/dead-store removal of byte-identical iterations (each rep re-loads
// and re-stores; output unchanged -> deterministic, validates fine).
//
// Forks (dur = 13.42 + 7*steady):
//   ~65-75us -> body throughput-bound (8us/rep); counters now in top-5 tell
//               which pipe. ~25-40 -> half of body is wave-latency; attack
//               TLP. ~16-22 -> single-shot is ramp-bound; at structural
//               floor -> declare roofline.
// ---------------------------------------------------------------------------
__global__ __launch_bounds__(256, 4) void sumconv_mfma(
        const float* __restrict__ x,
        const float* __restrict__ logits,
        float* __restrict__ out) {
    const int b = blockIdx.x;                     // 0..1023
    const int n = (b & 7) * 4 + ((b >> 3) & 3);   // image (XCD-chunked)
    const int r = b >> 5;                         // row-pair 0..31

    const int t    = threadIdx.x;
    const int wave = t >> 6;                      // 0..3
    const int lane = t & 63;
    const int pr = wave >> 1;                     // row within pair
    const int u  = wave & 1;                      // px half (cols 32u..32u+31)
    const int l15 = lane & 15, kb = lane >> 4;
    const int h = 2 * r + pr;

    __shared__ short Wl[4][CO * CI];              // bf16 weights [par][co*32+ci], 8 KB

#pragma unroll 1
    for (int rep = 0; rep < REPS; ++rep) {
        asm volatile("" ::: "memory");            // block cross-rep CSE/DSE

        // ---- x loads first: 8 coalesced float2 (both parities per lane) ----
        const float* xp = x + ((n * CI + kb * 8) * HH + h) * WW + 32 * u + 2 * l15;
        float2 xv[8];
#pragma unroll
        for (int i = 0; i < 8; ++i) xv[i] = *(const float2*)(xp + i * PLANE);

        // ---- phase 0: softmax -> LDS bf16 (128 active threads) ----
        if (t < 128) {
            const int co = t >> 2, par = t & 3;
            const float* base = logits + (co * CI) * 4 + par;
            float e[CI];
            float ssum = 0.0f;
#pragma unroll
            for (int ci = 0; ci < CI; ++ci) { e[ci] = __expf(base[ci * 4]); ssum += e[ci]; }
            const float inv = 1.0f / ssum;
#pragma unroll
            for (int ci = 0; ci < CI; ++ci) Wl[par][co * CI + ci] = f2bf(e[ci] * inv);
        }
        __syncthreads();

        // ---- A-frags: parities 2*pr (even col) and 2*pr+1 (odd col) ----
        const int parE = 2 * pr, parO = 2 * pr + 1;
        const bf16x8 aE0 = *(const bf16x8*)&Wl[parE][(l15     ) * CI + kb * 8];
        const bf16x8 aE1 = *(const bf16x8*)&Wl[parE][(l15 + 16) * CI + kb * 8];
        const bf16x8 aO0 = *(const bf16x8*)&Wl[parO][(l15     ) * CI + kb * 8];
        const bf16x8 aO1 = *(const bf16x8*)&Wl[parO][(l15 + 16) * CI + kb * 8];

        // ---- exp(x) -> B-frags (even / odd parity) ----
        bf16x8 bE, bO;
#pragma unroll
        for (int i = 0; i < 8; ++i) {
            bE[i] = f2bf(__expf(xv[i].x));
            bO[i] = f2bf(__expf(xv[i].y));
        }

        // ---- 4 MFMAs: 2 parities x 2 co-halves (K=32) ----
        const f32x4 z = {0.f, 0.f, 0.f, 0.f};
        f32x4 cE0 = __builtin_amdgcn_mfma_f32_16x16x32_bf16(aE0, bE, z, 0, 0, 0);
        f32x4 cE1 = __builtin_amdgcn_mfma_f32_16x16x32_bf16(aE1, bE, z, 0, 0, 0);
        f32x4 cO0 = __builtin_amdgcn_mfma_f32_16x16x32_bf16(aO0, bO, z, 0, 0, 0);
        f32x4 cO1 = __builtin_amdgcn_mfma_f32_16x16x32_bf16(aO1, bO, z, 0, 0, 0);

        // ---- log + paired float2 stores. D: col(pair)=l15, row(co)=4*kb+reg ----
        const int wc = 32 * u + 2 * l15;
        float* ob = out + ((n * CO + 4 * kb) * HH + h) * WW + wc;   // co base 4*kb
#pragma unroll
        for (int reg = 0; reg < 4; ++reg) {
            v2f lo, hi;
            lo.x = __logf(cE0[reg]); lo.y = __logf(cO0[reg]);       // co = 4kb+reg
            hi.x = __logf(cE1[reg]); hi.y = __logf(cO1[reg]);       // co = 16+4kb+reg
            *(v2f*)(ob + (reg     ) * PLANE) = lo;
            *(v2f*)(ob + (reg + 16) * PLANE) = hi;
        }

        __syncthreads();                          // reps can't overlap phase0 of next
    }
}

extern "C" void kernel_launch(void* const* d_in, const int* in_sizes, int n_in,
                              void* d_out, int out_size, void* d_ws, size_t ws_size,
                              hipStream_t stream) {
    const float* x      = (const float*)d_in[0];
    const float* logits = (const float*)d_in[1];
    float* out = (float*)d_out;

    sumconv_mfma<<<NN * (HH / 2), 256, 0, stream>>>(x, logits, out);
}

// Round 14
// 17.512 us; speedup vs baseline: 2.3580x; 2.3580x over previous
//
#include <hip/hip_runtime.h>
#include <math.h>

// Problem constants: N=32, CI=32, CO=32, H=64, W=64, K=2
#define NN 32
#define CI 32
#define CO 32
#define HH 64
#define WW 64
#define PLANE (HH * WW)

typedef __attribute__((ext_vector_type(8))) short bf16x8;   // MFMA A/B frag
typedef __attribute__((ext_vector_type(4))) float f32x4;    // MFMA C/D frag
typedef float v2f __attribute__((ext_vector_type(2)));

// float -> bf16 (round-to-nearest-even)
__device__ inline short f2bf(float f) {
    union { float f; unsigned u; } v; v.f = f;
    unsigned r = v.u + 0x7FFFu + ((v.u >> 16) & 1u);
    return (short)(r >> 16);
}

// ---------------------------------------------------------------------------
// out[n,co,h,w] = log( sum_ci W[co,ci,par] * exp(x[n,ci,h,w]) ),
//   W = softmax(logits over ci), par = (h&1)*2 + (w&1).
//
// R13 aborted on a GRID BUG (launched 4096 blocks, kernel decodes 2048 ->
// blocks 2048+ read co up to 63, OOB fault). Fixed: grid = 2048. Theory
// from R13 (untested until now):
//
//  - NO LDS, NO barrier: each lane computes its 16 softmax weights in
//    register. R8's failure was ordering (logits VMEM issued after x ->
//    vmcnt FIFO drain). Fixed: logits loads (L2-hot, ~200cy) FIRST,
//    x loads second; weight math overlaps x flight (waits at vmcnt(8)).
//  - co-half split across blocks: wave = (row, px-half), block owns one
//    co-half c -> 2 MFMAs, 8 outs/lane; 2048 blocks = 8 blocks/CU =
//    32 waves/CU (2x occupancy vs R11). Fine waves de-phase -> some
//    waves' cold reads overlap others' write drains (ramp reduction).
//  - x read 2x logically (c=0,1) but both c-blocks land on the same XCD
//    (same bits) -> second read is L2-hit.
//
// A-frag row = l15 -> co = 16c+l15; k = kb*8+i (identical indexing on B ->
// contraction-invariant). D: col=l15, row=4*kb+reg (HW-validated R7-R12).
// XCD swizzle: XCD k owns images 4k..4k+3 (2 MB slab) for all (r, c).
// ---------------------------------------------------------------------------
__global__ __launch_bounds__(256, 8) void sumconv_mfma(
        const float* __restrict__ x,
        const float* __restrict__ logits,
        float* __restrict__ out) {
    const int b = blockIdx.x;                     // 0..2047
    const int xcd = b & 7;
    const int s = b >> 3;                         // 0..255
    const int n = xcd * 4 + (s & 3);              // image (XCD-chunked)
    const int r = (s >> 2) & 31;                  // row-pair 0..31
    const int c = s >> 7;                         // co-half 0..1

    const int t    = threadIdx.x;
    const int wave = t >> 6;                      // 0..3
    const int lane = t & 63;
    const int pr = wave >> 1;                     // row within pair
    const int u  = wave & 1;                      // px half (cols 32u..32u+31)
    const int l15 = lane & 15, kb = lane >> 4;
    const int h  = 2 * r + pr;
    const int co = 16 * c + l15;                  // A-frag row for this lane

    // ---- (1) logits loads FIRST: 8 float2 (parities 2pr, 2pr+1), L2-hot ----
    const float* lp = logits + (co * CI + kb * 8) * 4 + 2 * pr;
    float2 lw[8];
#pragma unroll
    for (int i = 0; i < 8; ++i) lw[i] = *(const float2*)(lp + i * 4);

    // ---- (2) x loads second: 8 coalesced float2 (both col-parities) ----
    const float* xp = x + ((n * CI + kb * 8) * HH + h) * WW + 32 * u + 2 * l15;
    float2 xv[8];
#pragma unroll
    for (int i = 0; i < 8; ++i) xv[i] = *(const float2*)(xp + i * PLANE);

    // ---- (3) in-register softmax (overlaps x flight; waits vmcnt(8)) ----
    // logits in [log(1e-6), 0] -> exp safe without max pass.
    float eE[8], eO[8];
    float sE = 0.f, sO = 0.f;
#pragma unroll
    for (int i = 0; i < 8; ++i) {
        eE[i] = __expf(lw[i].x); sE += eE[i];     // par = 2pr   (even col)
        eO[i] = __expf(lw[i].y); sO += eO[i];     // par = 2pr+1 (odd col)
    }
    sE += __shfl_xor(sE, 16); sE += __shfl_xor(sE, 32);   // full-ci sum over kb
    sO += __shfl_xor(sO, 16); sO += __shfl_xor(sO, 32);
    const float iE = 1.f / sE, iO = 1.f / sO;

    bf16x8 aE, aO;
#pragma unroll
    for (int i = 0; i < 8; ++i) {
        aE[i] = f2bf(eE[i] * iE);
        aO[i] = f2bf(eO[i] * iO);
    }

    // ---- (4) exp(x) -> B-frags (waits vmcnt(0); x landed during (3)) ----
    bf16x8 bE, bO;
#pragma unroll
    for (int i = 0; i < 8; ++i) {
        bE[i] = f2bf(__expf(xv[i].x));
        bO[i] = f2bf(__expf(xv[i].y));
    }

    // ---- (5) 2 MFMAs: even/odd parity (K=32) ----
    const f32x4 z = {0.f, 0.f, 0.f, 0.f};
    f32x4 cE = __builtin_amdgcn_mfma_f32_16x16x32_bf16(aE, bE, z, 0, 0, 0);
    f32x4 cO = __builtin_amdgcn_mfma_f32_16x16x32_bf16(aO, bO, z, 0, 0, 0);

    // ---- (6) log + paired float2 stores. D: col=l15, row=4*kb+reg ----
    const int wc = 32 * u + 2 * l15;
    float* ob = out + ((n * CO + 16 * c + 4 * kb) * HH + h) * WW + wc;
#pragma unroll
    for (int reg = 0; reg < 4; ++reg) {
        v2f o;
        o.x = __logf(cE[reg]);                    // even col
        o.y = __logf(cO[reg]);                    // odd col
        *(v2f*)(ob + reg * PLANE) = o;
    }
}

extern "C" void kernel_launch(void* const* d_in, const int* in_sizes, int n_in,
                              void* d_out, int out_size, void* d_ws, size_t ws_size,
                              hipStream_t stream) {
    const float* x      = (const float*)d_in[0];
    const float* logits = (const float*)d_in[1];
    float* out = (float*)d_out;

    // images(32) x row-pairs(32) x co-halves(2) = 2048 blocks
    sumconv_mfma<<<NN * (HH / 2) * 2, 256, 0, stream>>>(x, logits, out);
}

// Round 15
// 10.947 us; speedup vs baseline: 3.7722x; 1.5997x over previous
//
#include <hip/hip_runtime.h>
#include <math.h>

// Problem constants: N=32, CI=32, CO=32, H=64, W=64, K=2
#define NN 32
#define CI 32
#define CO 32
#define HH 64
#define WW 64
#define PLANE (HH * WW)

typedef __attribute__((ext_vector_type(8))) short bf16x8;   // MFMA A/B frag
typedef __attribute__((ext_vector_type(4))) float f32x4;    // MFMA C/D frag
typedef float v4f __attribute__((ext_vector_type(4)));

// float -> bf16 (round-to-nearest-even)
__device__ inline short f2bf(float f) {
    union { float f; unsigned u; } v; v.f = f;
    unsigned r = v.u + 0x7FFFu + ((v.u >> 16) & 1u);
    return (short)(r >> 16);
}

// ---------------------------------------------------------------------------
// out[n,co,h,w] = log( sum_ci W[co,ci,par] * exp(x[n,ci,h,w]) ),
//   W = softmax(logits over ci), par = (h&1)*2 + (w&1).
//
// R14 post-mortem: in-register softmax on every wave's critical path lost to
// LDS phase0 (again); 32 waves/CU ~= 16 (TLP not binding). Remaining lead:
// R12 steady-state writes ran 3.3 TB/s with 8B/lane dwordx2 stores, while
// the harness fill (16B/lane dwordx4) sustains 6.4 TB/s on the same memory.
// This round tests VMEM WIDTH at constant occupancy:
//
//   wave = one full row; lane owns 4 consecutive cols (4*l15..+3) = both
//   parities x 2 slots -> float4 x-loads AND float4 NT stores (16B/lane,
//   half the VMEM instructions per byte). Block = (n, row-quad, co-half):
//   4 waves = 4 rows; 4 MFMAs/wave (par E/O x col-slot 0/1).
//   Cost: x read 2x (per co-half, L2-hit on same XCD), exp 2x (~0.9us,
//   overlappable). Keep R11 skeleton: x-loads first, LDS phase0, 1 barrier.
//
// A: row=l15 (co=16c+l15), k=kb*8+i. B: col=l15 (px 4*l15+slot), same k.
// D: col=l15, row=4*kb+reg (HW-validated R7-R14).
// XCD swizzle: XCD k owns images 4k..4k+3 (2 MB slab) for all (rq, c).
// ---------------------------------------------------------------------------
__global__ __launch_bounds__(256, 4) void sumconv_mfma(
        const float* __restrict__ x,
        const float* __restrict__ logits,
        float* __restrict__ out) {
    const int b   = blockIdx.x;                   // 0..1023
    const int xcd = b & 7;
    const int s   = b >> 3;                       // 0..127
    const int n   = xcd * 4 + (s & 3);            // image (XCD-chunked)
    const int rq  = (s >> 2) & 15;                // row-quad 0..15
    const int c   = (s >> 6) & 1;                 // co-half 0..1

    const int t    = threadIdx.x;
    const int wave = t >> 6;                      // 0..3 = row in quad
    const int lane = t & 63;
    const int l15 = lane & 15, kb = lane >> 4;
    const int h  = 4 * rq + wave;
    const int pr = h & 1;                         // row parity

    __shared__ short Wl[4][16 * CI];              // bf16 [par][co_l*32+ci], 4 KB

    // ---- (1) x loads first: 8 coalesced float4 (4 cols/lane) ----
    const float* xp = x + ((n * CI + kb * 8) * HH + h) * WW + 4 * l15;
    float4 xv[8];
#pragma unroll
    for (int i = 0; i < 8; ++i) xv[i] = *(const float4*)(xp + i * PLANE);

    // ---- (2) phase 0: softmax -> LDS bf16 (64 active threads) ----
    if (t < 64) {
        const int co_l = t >> 2, par = t & 3;
        const float* base = logits + ((16 * c + co_l) * CI) * 4 + par;
        float e[CI];
        float ssum = 0.0f;
#pragma unroll
        for (int ci = 0; ci < CI; ++ci) { e[ci] = __expf(base[ci * 4]); ssum += e[ci]; }
        const float inv = 1.0f / ssum;
#pragma unroll
        for (int ci = 0; ci < CI; ++ci) Wl[par][co_l * CI + ci] = f2bf(e[ci] * inv);
    }
    __syncthreads();

    // ---- (3) A-frags: parities 2pr (even col), 2pr+1 (odd col) ----
    const bf16x8 aE = *(const bf16x8*)&Wl[2 * pr    ][l15 * CI + kb * 8];
    const bf16x8 aO = *(const bf16x8*)&Wl[2 * pr + 1][l15 * CI + kb * 8];

    // ---- (4) exp(x) -> 4 B-frags (col slots: 4l15+{0,1,2,3}) ----
    bf16x8 bE0, bO0, bE1, bO1;
#pragma unroll
    for (int i = 0; i < 8; ++i) {
        bE0[i] = f2bf(__expf(xv[i].x));           // px 4l15+0 (even)
        bO0[i] = f2bf(__expf(xv[i].y));           // px 4l15+1 (odd)
        bE1[i] = f2bf(__expf(xv[i].z));           // px 4l15+2 (even)
        bO1[i] = f2bf(__expf(xv[i].w));           // px 4l15+3 (odd)
    }

    // ---- (5) 4 MFMAs (K=32): par x col-slot ----
    const f32x4 z = {0.f, 0.f, 0.f, 0.f};
    f32x4 cE0 = __builtin_amdgcn_mfma_f32_16x16x32_bf16(aE, bE0, z, 0, 0, 0);
    f32x4 cO0 = __builtin_amdgcn_mfma_f32_16x16x32_bf16(aO, bO0, z, 0, 0, 0);
    f32x4 cE1 = __builtin_amdgcn_mfma_f32_16x16x32_bf16(aE, bE1, z, 0, 0, 0);
    f32x4 cO1 = __builtin_amdgcn_mfma_f32_16x16x32_bf16(aO, bO1, z, 0, 0, 0);

    // ---- (6) log + float4 NT stores (16B/lane). D: col=l15, row=4kb+reg ----
    float* ob = out + ((n * CO + 16 * c + 4 * kb) * HH + h) * WW + 4 * l15;
#pragma unroll
    for (int reg = 0; reg < 4; ++reg) {
        v4f o;
        o.x = __logf(cE0[reg]);
        o.y = __logf(cO0[reg]);
        o.z = __logf(cE1[reg]);
        o.w = __logf(cO1[reg]);
        __builtin_nontemporal_store(o, (v4f*)(ob + reg * PLANE));
    }
}

extern "C" void kernel_launch(void* const* d_in, const int* in_sizes, int n_in,
                              void* d_out, int out_size, void* d_ws, size_t ws_size,
                              hipStream_t stream) {
    const float* x      = (const float*)d_in[0];
    const float* logits = (const float*)d_in[1];
    float* out = (float*)d_out;

    // images(32) x row-quads(16) x co-halves(2) = 1024 blocks
    sumconv_mfma<<<NN * (HH / 4) * 2, 256, 0, stream>>>(x, logits, out);
}

// Round 16
// 10.699 us; speedup vs baseline: 3.8594x; 1.0231x over previous
//
#include <hip/hip_runtime.h>
#include <math.h>

// Problem constants: N=32, CI=32, CO=32, H=64, W=64, K=2
#define NN 32
#define CI 32
#define CO 32
#define HH 64
#define WW 64
#define PLANE (HH * WW)

typedef __attribute__((ext_vector_type(8))) short bf16x8;   // MFMA A/B frag
typedef __attribute__((ext_vector_type(4))) float f32x4;    // MFMA C/D frag
typedef float v4f __attribute__((ext_vector_type(4)));

// float -> bf16 (round-to-nearest-even)
__device__ inline short f2bf(float f) {
    union { float f; unsigned u; } v; v.f = f;
    unsigned r = v.u + 0x7FFFu + ((v.u >> 16) & 1u);
    return (short)(r >> 16);
}

// ---------------------------------------------------------------------------
// out[n,co,h,w] = log( sum_ci W[co,ci,par] * exp(x[n,ci,h,w]) ),
//   W = softmax(logits over ci), par = (h&1)*2 + (w&1).
//
// R15 confirmed VMEM width as the bottleneck (float4 both sides: 13.4->10.9).
// This round removes the last visible redundancy: the co-half split ran the
// whole x side TWICE (x L2 reads, 8.4M exps, phase0 x1024) even though
// B-frags are co-independent. Merge: wave = one row x FULL CO ->
// the same 4 B-frags feed 8 MFMAs (2 co-halves x par x col-slot) IN REGISTER.
//
//   Block = (image, row-quad): 512 blocks, 4 waves = 4 rows.
//   acc = 8 x f32x4 = 32 VGPR; __launch_bounds__(256,2) (8 waves/CU).
//   exp once per element (4.2M), x read once per (n,h) through L2.
//
// Keep R15's proven parts: float4 x-loads first, LDS phase0 softmax (now
// 128 threads, full CO), one barrier, float4 NT stores, XCD swizzle
// (XCD k owns images 4k..4k+3), D: col=l15, row=4*kb+reg (HW-validated).
//
// Pre-commit: if this is neutral/regressed vs 10.95, occupancy-2/SIMD is
// the cause -> revert to R15 and declare roofline (floor model ~10.1us).
// ---------------------------------------------------------------------------
__global__ __launch_bounds__(256, 2) void sumconv_mfma(
        const float* __restrict__ x,
        const float* __restrict__ logits,
        float* __restrict__ out) {
    const int b   = blockIdx.x;                   // 0..511
    const int xcd = b & 7;
    const int s   = b >> 3;                       // 0..63
    const int n   = xcd * 4 + (s & 3);            // image (XCD-chunked)
    const int rq  = s >> 2;                       // row-quad 0..15

    const int t    = threadIdx.x;
    const int wave = t >> 6;                      // 0..3 = row in quad
    const int lane = t & 63;
    const int l15 = lane & 15, kb = lane >> 4;
    const int h  = 4 * rq + wave;
    const int pr = h & 1;                         // row parity

    __shared__ short Wl[4][CO * CI];              // bf16 [par][co*32+ci], 8 KB

    // ---- (1) x loads first: 8 coalesced float4 (4 cols/lane) ----
    const float* xp = x + ((n * CI + kb * 8) * HH + h) * WW + 4 * l15;
    float4 xv[8];
#pragma unroll
    for (int i = 0; i < 8; ++i) xv[i] = *(const float4*)(xp + i * PLANE);

    // ---- (2) phase 0: softmax -> LDS bf16 (128 active threads, full CO) ----
    if (t < 128) {
        const int co = t >> 2, par = t & 3;
        const float* base = logits + (co * CI) * 4 + par;
        float e[CI];
        float ssum = 0.0f;
#pragma unroll
        for (int ci = 0; ci < CI; ++ci) { e[ci] = __expf(base[ci * 4]); ssum += e[ci]; }
        const float inv = 1.0f / ssum;
#pragma unroll
        for (int ci = 0; ci < CI; ++ci) Wl[par][co * CI + ci] = f2bf(e[ci] * inv);
    }
    __syncthreads();

    // ---- (3) A-frags: 2 parities x 2 co-halves ----
    const bf16x8 aE0 = *(const bf16x8*)&Wl[2 * pr    ][(l15     ) * CI + kb * 8];
    const bf16x8 aO0 = *(const bf16x8*)&Wl[2 * pr + 1][(l15     ) * CI + kb * 8];
    const bf16x8 aE1 = *(const bf16x8*)&Wl[2 * pr    ][(l15 + 16) * CI + kb * 8];
    const bf16x8 aO1 = *(const bf16x8*)&Wl[2 * pr + 1][(l15 + 16) * CI + kb * 8];

    // ---- (4) exp(x) -> 4 B-frags (col slots 4l15+{0..3}), co-independent ----
    bf16x8 bE0, bO0, bE1, bO1;
#pragma unroll
    for (int i = 0; i < 8; ++i) {
        bE0[i] = f2bf(__expf(xv[i].x));           // px 4l15+0 (even)
        bO0[i] = f2bf(__expf(xv[i].y));           // px 4l15+1 (odd)
        bE1[i] = f2bf(__expf(xv[i].z));           // px 4l15+2 (even)
        bO1[i] = f2bf(__expf(xv[i].w));           // px 4l15+3 (odd)
    }

    // ---- (5) 8 MFMAs (K=32): B-frags reused across both co-halves ----
    const f32x4 z = {0.f, 0.f, 0.f, 0.f};
    f32x4 cE0h0 = __builtin_amdgcn_mfma_f32_16x16x32_bf16(aE0, bE0, z, 0, 0, 0);
    f32x4 cO0h0 = __builtin_amdgcn_mfma_f32_16x16x32_bf16(aO0, bO0, z, 0, 0, 0);
    f32x4 cE1h0 = __builtin_amdgcn_mfma_f32_16x16x32_bf16(aE0, bE1, z, 0, 0, 0);
    f32x4 cO1h0 = __builtin_amdgcn_mfma_f32_16x16x32_bf16(aO0, bO1, z, 0, 0, 0);
    f32x4 cE0h1 = __builtin_amdgcn_mfma_f32_16x16x32_bf16(aE1, bE0, z, 0, 0, 0);
    f32x4 cO0h1 = __builtin_amdgcn_mfma_f32_16x16x32_bf16(aO1, bO0, z, 0, 0, 0);
    f32x4 cE1h1 = __builtin_amdgcn_mfma_f32_16x16x32_bf16(aE1, bE1, z, 0, 0, 0);
    f32x4 cO1h1 = __builtin_amdgcn_mfma_f32_16x16x32_bf16(aO1, bO1, z, 0, 0, 0);

    // ---- (6) log + float4 NT stores (16B/lane). D: col=l15, row=4kb+reg ----
    float* ob0 = out + ((n * CO +      4 * kb) * HH + h) * WW + 4 * l15;  // half 0
    float* ob1 = out + ((n * CO + 16 + 4 * kb) * HH + h) * WW + 4 * l15;  // half 1
#pragma unroll
    for (int reg = 0; reg < 4; ++reg) {
        v4f o0, o1;
        o0.x = __logf(cE0h0[reg]);
        o0.y = __logf(cO0h0[reg]);
        o0.z = __logf(cE1h0[reg]);
        o0.w = __logf(cO1h0[reg]);
        o1.x = __logf(cE0h1[reg]);
        o1.y = __logf(cO0h1[reg]);
        o1.z = __logf(cE1h1[reg]);
        o1.w = __logf(cO1h1[reg]);
        __builtin_nontemporal_store(o0, (v4f*)(ob0 + reg * PLANE));
        __builtin_nontemporal_store(o1, (v4f*)(ob1 + reg * PLANE));
    }
}

extern "C" void kernel_launch(void* const* d_in, const int* in_sizes, int n_in,
                              void* d_out, int out_size, void* d_ws, size_t ws_size,
                              hipStream_t stream) {
    const float* x      = (const float*)d_in[0];
    const float* logits = (const float*)d_in[1];
    float* out = (float*)d_out;

    // images(32) x row-quads(16) = 512 blocks
    sumconv_mfma<<<NN * (HH / 4), 256, 0, stream>>>(x, logits, out);
}